// Round 3
// baseline (406.702 us; speedup 1.0000x reference)
//
#include <hip/hip_runtime.h>

// B=8, L=2048, H=1024. fp32 in/out, bf16 MFMA internally.
// Pipeline: convert -> gemm8p<0> (QKV proj) -> transpose V -> gemm8p<1> (P=exp(QK^T), diag=0, fused row-sum)
//           -> gemm8p<2> (out = P@V / denom)
// gemm8p: 256x256 tile, BK=64, 8 waves (2x4), 4-phase/tile pipelined schedule:
//   - ds_reads issued one phase AHEAD of their MFMA use (compiler emits counted lgkm waits)
//   - staging 2 tiles ahead into 4 DISTINCT __shared__ objects (alias-analysis-visible),
//     so LDS-DMA hazard waits cover loads >= 4 phases old (>= HBM latency) => ~free
//   - raw s_barrier pairs per phase, setprio(1) around MFMA clusters (T5)

typedef unsigned short u16;
typedef __bf16 bfx8 __attribute__((ext_vector_type(8)));
typedef float f32x4 __attribute__((ext_vector_type(4)));

__device__ __forceinline__ u16 f2bf(float f) {
    unsigned int x = __float_as_uint(f);
    unsigned int r = (x + 0x7fffu + ((x >> 16) & 1u)) >> 16;  // RNE
    return (u16)r;
}
__device__ __forceinline__ float bf2f(u16 u) {
    return __uint_as_float(((unsigned int)u) << 16);
}

// ---------------- fp32 -> bf16 convert (8 elems/thread) ----------------
__global__ void f32_to_bf16(const float* __restrict__ src, u16* __restrict__ dst, int n8) {
    int i = blockIdx.x * blockDim.x + threadIdx.x;
    if (i < n8) {
        float4 a = ((const float4*)src)[i * 2];
        float4 b = ((const float4*)src)[i * 2 + 1];
        ushort4 lo; lo.x = f2bf(a.x); lo.y = f2bf(a.y); lo.z = f2bf(a.z); lo.w = f2bf(a.w);
        ushort4 hi; hi.x = f2bf(b.x); hi.y = f2bf(b.y); hi.z = f2bf(b.z); hi.w = f2bf(b.w);
        ((ushort4*)dst)[i * 2] = lo;
        ((ushort4*)dst)[i * 2 + 1] = hi;
    }
}

// ---------------- bf16 transpose: [8][2048][1024] -> [8][1024][2048] ----------------
__global__ void transpose_bf16(const u16* __restrict__ src, u16* __restrict__ dst) {
    __shared__ u16 s[64][64 + 8];
    int z = blockIdx.z;
    int tm = blockIdx.x * 64;
    int th = blockIdx.y * 64;
    const u16* sp = src + (long)z * 2048 * 1024;
    u16* dp = dst + (long)z * 1024 * 2048;
    int t = threadIdx.x;
#pragma unroll
    for (int p = 0; p < 4; ++p) {
        int r = p * 16 + (t >> 4);
        int c = (t & 15) * 4;
        ushort4 v = *(const ushort4*)(sp + (long)(tm + r) * 1024 + th + c);
        s[r][c] = v.x; s[r][c + 1] = v.y; s[r][c + 2] = v.z; s[r][c + 3] = v.w;
    }
    __syncthreads();
#pragma unroll
    for (int p = 0; p < 4; ++p) {
        int hr = p * 16 + (t >> 4);
        int c = (t & 15) * 4;
        ushort4 v;
        v.x = s[c][hr]; v.y = s[c + 1][hr]; v.z = s[c + 2][hr]; v.w = s[c + 3][hr];
        *(ushort4*)(dp + (long)(th + hr) * 2048 + tm + c) = v;
    }
}

// ---------------- 256x256 pipelined NT GEMM ----------------
// C[M,N] = A[M,K] @ B[N,K]^T, bf16 in, fp32 acc.

#define FENCE asm volatile("" ::: "memory")
#define BAR   __builtin_amdgcn_s_barrier()
#define PRIO1 __builtin_amdgcn_s_setprio(1)
#define PRIO0 __builtin_amdgcn_s_setprio(0)

// stage a full 32KB tile (256 rows x 64 k bf16) into DST (distinct static __shared__ array)
#define STAGEF(DST, SRC, LD, tt) do{ \
    _Pragma("unroll") \
    for (int rnd = 0; rnd < 4; ++rnd) { \
        int c_ = rnd * 512 + tid; \
        int row_ = c_ >> 3; \
        int slot_ = c_ & 7; \
        const u16* g_ = (SRC) + (long)row_ * (LD) + (tt) * 64 + ((slot_ ^ (row_ & 7)) << 3); \
        char* l_ = (char*)(DST) + rnd * 8192 + wid * 1024; \
        __builtin_amdgcn_global_load_lds((__attribute__((address_space(1))) void*)g_, \
            (__attribute__((address_space(3))) void*)l_, 16, 0, 0); \
    } \
}while(0)

#define RD_A4(dst, SARR, mibase) do{ \
    const char* _b = (const char*)(SARR) + ((wr * 128 + (mibase) * 16 + rA) * 128); \
    dst[0][0] = *(const bfx8*)(_b + 0 * 2048 + ofk0); dst[0][1] = *(const bfx8*)(_b + 0 * 2048 + ofk1); \
    dst[1][0] = *(const bfx8*)(_b + 1 * 2048 + ofk0); dst[1][1] = *(const bfx8*)(_b + 1 * 2048 + ofk1); \
    dst[2][0] = *(const bfx8*)(_b + 2 * 2048 + ofk0); dst[2][1] = *(const bfx8*)(_b + 2 * 2048 + ofk1); \
    dst[3][0] = *(const bfx8*)(_b + 3 * 2048 + ofk0); dst[3][1] = *(const bfx8*)(_b + 3 * 2048 + ofk1); \
}while(0)

#define RD_B2(dst, SARR, nibase) do{ \
    const char* _b = (const char*)(SARR) + ((wc * 64 + (nibase) * 16 + rA) * 128); \
    dst[0][0] = *(const bfx8*)(_b + 0 * 2048 + ofk0); dst[0][1] = *(const bfx8*)(_b + 0 * 2048 + ofk1); \
    dst[1][0] = *(const bfx8*)(_b + 1 * 2048 + ofk0); dst[1][1] = *(const bfx8*)(_b + 1 * 2048 + ofk1); \
}while(0)

#define MMQ(AS, BS, M0, N0) do{ \
    _Pragma("unroll") \
    for (int ks = 0; ks < 2; ++ks) \
    _Pragma("unroll") \
    for (int mi = 0; mi < 4; ++mi) \
    _Pragma("unroll") \
    for (int ni = 0; ni < 2; ++ni) \
        acc[(M0)+mi][(N0)+ni] = __builtin_amdgcn_mfma_f32_16x16x32_bf16(AS[mi][ks], BS[ni][ks], acc[(M0)+mi][(N0)+ni], 0, 0, 0); \
}while(0)

// One K-tile, 4 phases. Reads tile tt from {SA_R,SB_R}; A(tt+1) frag-prefetch from SA_O;
// stages tile tt+2 into {SA_R,SB_R}. Quadrants: (0,0) (0,2) (4,2) (4,0).
#define TILE(SA_R, SB_R, SA_O, tt) do{ \
    /* P1: issue b01(tt), b23(tt); MFMA Q(0,0) [aA: issued last tile P4; b01: this phase (small wait)] */ \
    RD_B2(b01, SB_R, 0); RD_B2(b23, SB_R, 2); \
    FENCE; BAR; PRIO1; MMQ(aA, b01, 0, 0); PRIO0; FENCE; BAR; \
    /* P2: issue aB(tt); MFMA Q(0,2) [aA, b23: issued P1] */ \
    RD_A4(aB, SA_R, 4); \
    FENCE; BAR; PRIO1; MMQ(aA, b23, 0, 2); PRIO0; FENCE; BAR; \
    /* P3: drain old DMAs (issued >=4 phases ago); stage B(tt+2); MFMA Q(4,2) [aB: P2] */ \
    asm volatile("s_waitcnt vmcnt(0)" ::: "memory"); \
    if ((tt) + 2 < NT) STAGEF(SB_R, B, ldb, (tt) + 2); \
    FENCE; BAR; PRIO1; MMQ(aB, b23, 4, 2); PRIO0; FENCE; BAR; \
    /* P4: issue aA(tt+1) from other buf; stage A(tt+2); MFMA Q(4,0) [aB, b01: done] */ \
    RD_A4(aA, SA_O, 0); \
    if ((tt) + 2 < NT) STAGEF(SA_R, A, lda, (tt) + 2); \
    FENCE; BAR; PRIO1; MMQ(aB, b01, 4, 0); PRIO0; FENCE; BAR; \
}while(0)

// MODE 0: +biasCat[col]; col<1024 scaled 1/1024; store bf16 to q/k/v.
// MODE 1: p=(row==col)?0:exp(acc); store bf16 P; fused row-sum atomicAdd -> den.
// MODE 2: out = acc / den[row]; store fp32.
template <int MODE>
__global__ __launch_bounds__(512, 2) void gemm8p(
    const u16* __restrict__ Ab, const u16* __restrict__ Bb,
    int K, int lda, int ldb,
    long strideA, long strideB,
    const float* __restrict__ biasCat,
    u16* __restrict__ outBf, long strideP,
    float* __restrict__ den,
    float* __restrict__ outF)
{
    // four DISTINCT static LDS objects => alias analysis can prove cross-buffer NoAlias
    __shared__ __align__(16) u16 sA0[16384];
    __shared__ __align__(16) u16 sB0[16384];
    __shared__ __align__(16) u16 sA1[16384];
    __shared__ __align__(16) u16 sB1[16384];

    const int tid  = threadIdx.x;
    const int lane = tid & 63;
    const int wid  = tid >> 6;
    const int wr = wid >> 2, wc = wid & 3;   // 2x4 wave grid; wave tile 128x64
    const int z = blockIdx.z;
    const u16* A = Ab + (long)z * strideA + (long)blockIdx.x * 256 * lda;
    const u16* B = Bb + (long)z * strideB + (long)blockIdx.y * 256 * ldb;
    const int NT = K >> 6;

    const int rA  = lane & 15;
    const int cg  = lane >> 4;
    const int swz = rA & 7;
    const int ofk0 = ((cg)     ^ swz) << 4;
    const int ofk1 = ((cg | 4) ^ swz) << 4;

    f32x4 acc[8][4] = {};
    bfx8 aA[4][2], aB[4][2], b01[2][2], b23[2][2];

    // prologue: stage tiles 0 and 1 fully; wait tile0; prefetch aA(0)
    STAGEF(sA0, A, lda, 0); STAGEF(sB0, B, ldb, 0);
    STAGEF(sA1, A, lda, 1); STAGEF(sB1, B, ldb, 1);
    asm volatile("s_waitcnt vmcnt(8)" ::: "memory");
    BAR;
    RD_A4(aA, sA0, 0);
    FENCE;

    for (int t = 0; t < NT; t += 2) {
        TILE(sA0, sB0, sA1, t);
        TILE(sA1, sB1, sA0, t + 1);
    }

    // epilogue: C frag row = cg*4 + r, col = rA within each 16x16
    const int r0 = blockIdx.x * 256 + wr * 128 + (cg << 2);
    const int c0 = blockIdx.y * 256 + wc * 64 + rA;
#pragma unroll
    for (int mi = 0; mi < 8; ++mi) {
#pragma unroll
        for (int r = 0; r < 4; ++r) {
            const int grow = r0 + mi * 16 + r;
            if constexpr (MODE == 0) {
#pragma unroll
                for (int ni = 0; ni < 4; ++ni) {
                    int gcol = c0 + ni * 16;
                    float v = acc[mi][ni][r] + biasCat[gcol];
                    if (gcol < 1024) v *= (1.0f / 1024.0f);  // fold 1/hidden into q (exact pow2)
                    int which = gcol >> 10;
                    long dst = (long)which * (16384L * 1024) + (long)grow * 1024 + (gcol & 1023);
                    outBf[dst] = f2bf(v);
                }
            } else if constexpr (MODE == 1) {
                float s = 0.0f;
#pragma unroll
                for (int ni = 0; ni < 4; ++ni) {
                    int gcol = c0 + ni * 16;
                    float p = (grow == gcol) ? 0.0f : __expf(acc[mi][ni][r]);  // |S| small: no max-sub
                    u16 pb = f2bf(p);
                    outBf[(long)z * strideP + (long)grow * 2048 + gcol] = pb;
                    s += bf2f(pb);  // denom from the SAME rounded values used in PV
                }
                s += __shfl_xor(s, 1); s += __shfl_xor(s, 2);
                s += __shfl_xor(s, 4); s += __shfl_xor(s, 8);
                if (rA == 0) atomicAdd(&den[z * 2048 + grow], s);
            } else {
                float d = den[z * 2048 + grow];
#pragma unroll
                for (int ni = 0; ni < 4; ++ni)
                    outF[(long)z * (2048L * 1024) + (long)grow * 1024 + (c0 + ni * 16)] = acc[mi][ni][r] / d;
            }
        }
    }
}

extern "C" void kernel_launch(void* const* d_in, const int* in_sizes, int n_in,
                              void* d_out, int out_size, void* d_ws, size_t ws_size,
                              hipStream_t stream) {
    const float* x  = (const float*)d_in[0];
    const float* Wq = (const float*)d_in[1];
    const float* bq = (const float*)d_in[2];
    const float* Wk = (const float*)d_in[3];
    const float* bk = (const float*)d_in[4];
    const float* Wv = (const float*)d_in[5];
    const float* bv = (const float*)d_in[6];
    float* out = (float*)d_out;

    // workspace layout (bytes); vT aliases dead xb, P overlays dead v
    const long XB_OFF   = 0;                         // xb: 33554432 ; later vT
    const long WB_OFF   = 33554432;                  // Wqkv bf16: 6291456
    const long BIAS_OFF = WB_OFF + 6291456;          // 12288
    const long DEN_OFF  = BIAS_OFF + 12288;          // 65536
    const long QKV_OFF  = DEN_OFF + 65536;           // q,k,v
    const long PB_OFF   = QKV_OFF + 2L * 33554432;   // P overlays v
    const unsigned long long NEED = (unsigned long long)(PB_OFF + 67108864);
    if (ws_size < NEED) return;

    char* ws = (char*)d_ws;
    u16*   xb      = (u16*)(ws + XB_OFF);
    u16*   vT      = (u16*)(ws + XB_OFF);
    u16*   Wb      = (u16*)(ws + WB_OFF);
    float* biasCat = (float*)(ws + BIAS_OFF);
    float* den     = (float*)(ws + DEN_OFF);
    u16*   qkv     = (u16*)(ws + QKV_OFF);
    u16*   qb = qkv;
    u16*   kb = qkv + 16384L * 1024;
    u16*   vb = qkv + 2L * 16384 * 1024;
    u16*   Pb = (u16*)(ws + PB_OFF);

    f32_to_bf16<<<8192, 256, 0, stream>>>(x, xb, 2097152);
    f32_to_bf16<<<512, 256, 0, stream>>>(Wq, Wb, 131072);
    f32_to_bf16<<<512, 256, 0, stream>>>(Wk, Wb + 1048576, 131072);
    f32_to_bf16<<<512, 256, 0, stream>>>(Wv, Wb + 2097152, 131072);
    hipMemcpyAsync(biasCat,        bq, 4096, hipMemcpyDeviceToDevice, stream);
    hipMemcpyAsync(biasCat + 1024, bk, 4096, hipMemcpyDeviceToDevice, stream);
    hipMemcpyAsync(biasCat + 2048, bv, 4096, hipMemcpyDeviceToDevice, stream);
    hipMemsetAsync(den, 0, 65536, stream);  // fused row-sum accumulates into this

    // QKV projection: [16384,1024] @ [3072,1024]^T
    gemm8p<0><<<dim3(64, 12, 1), 512, 0, stream>>>(
        xb, Wb, 1024, 1024, 1024, 0, 0, biasCat, qkv, 0, nullptr, nullptr);

    // V transpose per batch
    transpose_bf16<<<dim3(32, 16, 8), 256, 0, stream>>>(vb, vT);

    // P = exp(Q @ K^T), diag->0, bf16, fused row sums
    gemm8p<1><<<dim3(8, 8, 8), 512, 0, stream>>>(
        qb, kb, 1024, 1024, 1024, 2048L * 1024, 2048L * 1024,
        nullptr, Pb, 2048L * 2048, den, nullptr);

    // out = (P @ vT^T) / denom
    gemm8p<2><<<dim3(8, 4, 8), 512, 0, stream>>>(
        Pb, vT, 2048, 2048, 2048, 2048L * 2048, 1024L * 2048,
        nullptr, nullptr, 0, den, out);
}